// Round 3
// baseline (898.390 us; speedup 1.0000x reference)
//
#include <hip/hip_runtime.h>

#define EMBD 32
#define KN 10
#define NBLK 1536   // 6 blocks/CU x 256 CU; residency guaranteed (see launch_bounds note)

__device__ unsigned int g_cnt   = 0;
__device__ unsigned int g_epoch = 0;

__device__ __forceinline__ float bf2f(unsigned short u) {
    union { unsigned int u; float f; } c; c.u = ((unsigned int)u) << 16; return c.f;
}
__device__ __forceinline__ unsigned short f2bf(float f) {
    union { float f; unsigned int u; } c; c.f = f;
    unsigned int u = c.u + 0x7FFFu + ((c.u >> 16) & 1u);   // RNE
    return (unsigned short)(u >> 16);
}

// Device-scope epoch barrier. Monotone epoch -> safe across graph replays
// (no per-launch state reset needed). Plain atomics, no cooperative API ->
// graph-capture safe. Correct only if ALL gridDim.x blocks are resident:
// guaranteed by launch_bounds(256,6) (VGPR cap ~85) + LDS 19456 B/block
// (6 x 19456 = 114 KB <= 160 KB/CU) with grid = 6 blocks/CU x 256 CU.
__device__ __forceinline__ void gbar() {
    __syncthreads();                       // implies vmcnt(0): block's stores in L2
    if (threadIdx.x == 0) {
        __threadfence();                   // agent-scope release of this XCD's writes
        unsigned int e = __hip_atomic_load(&g_epoch, __ATOMIC_RELAXED,
                                           __HIP_MEMORY_SCOPE_AGENT);
        unsigned int a = __hip_atomic_fetch_add(&g_cnt, 1u, __ATOMIC_ACQ_REL,
                                                __HIP_MEMORY_SCOPE_AGENT);
        if (a == gridDim.x - 1) {          // last arriver
            __hip_atomic_store(&g_cnt, 0u, __ATOMIC_RELAXED,
                               __HIP_MEMORY_SCOPE_AGENT);
            __hip_atomic_fetch_add(&g_epoch, 1u, __ATOMIC_RELEASE,
                                   __HIP_MEMORY_SCOPE_AGENT);
        } else {
            while (__hip_atomic_load(&g_epoch, __ATOMIC_ACQUIRE,
                                     __HIP_MEMORY_SCOPE_AGENT) == e)
                __builtin_amdgcn_s_sleep(8);
        }
        __threadfence();                   // acquire side
    }
    __syncthreads();
}

// One fused SAGE tile (64 rows): index-stage -> gather-mean -> GEMM+ReLU.
// Same body as the round-1 kernel (96 us/L1, at the ~3.5 TB/s random-gather
// pattern ceiling). LDS passed in: declared ONCE in the kernel so the two
// template instantiations share the same 19456 B block (critical for the
// residency guarantee).
template<bool REMAP, bool OUT_BF16>
__device__ __forceinline__ void sage_tile(
    const unsigned short* __restrict__ feat,  // [n_nodes,32] bf16
    const float*          __restrict__ W,     // [32][64] f32
    const int*            __restrict__ neigh, // [N_NODES,10]
    const int*            __restrict__ remap, // row -> node (REMAP)
    void*                 __restrict__ out,   // [n_rows,32]
    int n_rows, int tile,
    float (* __restrict__ sh)[65],
    int   (* __restrict__ s_nb)[KN],
    int*     __restrict__ s_node)
{
    const int tid  = threadIdx.x;
    const int row0 = tile << 6;

    __syncthreads();                      // protect LDS from previous tile's readers

    if constexpr (REMAP) {
        if (tid < 64) {
            int r = row0 + tid;
            if (r >= n_rows) r = n_rows - 1;       // clamp; store guarded later
            s_node[tid] = remap[r];
        }
        __syncthreads();
    }

    // stage all 640 neighbor ids, fully parallel
    #pragma unroll
    for (int e = tid; e < 64 * KN; e += 256) {
        const int rl = e / KN;
        const int k  = e - rl * KN;
        int node;
        if constexpr (REMAP) node = s_node[rl];
        else { int r = row0 + rl; node = (r >= n_rows) ? n_rows - 1 : r; }
        s_nb[rl][k] = neigh[node * KN + k];
    }
    __syncthreads();

    // gather: half-wave per row, 64 B coalesced bf16 rows
    {
        const int hw = tid >> 5;
        const int j  = tid & 31;
        #pragma unroll 2
        for (int i = 0; i < 8; ++i) {
            const int rl = hw * 8 + i;
            int node;
            if constexpr (REMAP) node = s_node[rl];
            else { int r = row0 + rl; node = (r >= n_rows) ? n_rows - 1 : r; }
            const float self = bf2f(feat[node * EMBD + j]);
            float agg = 0.f;
            #pragma unroll
            for (int k = 0; k < KN; ++k)
                agg += bf2f(feat[s_nb[rl][k] * EMBD + j]);
            sh[j][rl]      = self;
            sh[32 + j][rl] = agg * 0.1f;
        }
    }
    __syncthreads();

    // compute: wave wid -> outputs [8wid, 8wid+8) for all 64 rows
    const int row = tid & 63;
    const int wid = __builtin_amdgcn_readfirstlane(tid >> 6);
    const float* Wb = W + wid * 8 * 64;   // wave-uniform -> scalar K$ loads

    float acc[8] = {0.f,0.f,0.f,0.f,0.f,0.f,0.f,0.f};
    #pragma unroll 8
    for (int jj = 0; jj < 64; ++jj) {
        const float c = sh[jj][row];      // stride-1 across lanes: conflict-free
        #pragma unroll
        for (int q = 0; q < 8; ++q)
            acc[q] = fmaf(c, Wb[q * 64 + jj], acc[q]);
    }

    const int r = row0 + row;
    if (r < n_rows) {
        if constexpr (OUT_BF16) {
            unsigned int pk[4];
            #pragma unroll
            for (int q = 0; q < 4; ++q) {
                float a0 = fmaxf(acc[2*q],     0.f);
                float a1 = fmaxf(acc[2*q + 1], 0.f);
                pk[q] = (unsigned int)f2bf(a0) | ((unsigned int)f2bf(a1) << 16);
            }
            uint4* dst = (uint4*)((unsigned short*)out + (size_t)r * EMBD + wid * 8);
            *dst = make_uint4(pk[0], pk[1], pk[2], pk[3]);
        } else {
            float* dst = (float*)out + (size_t)r * EMBD + wid * 8;
            ((float4*)dst)[0] = make_float4(fmaxf(acc[0],0.f), fmaxf(acc[1],0.f),
                                            fmaxf(acc[2],0.f), fmaxf(acc[3],0.f));
            ((float4*)dst)[1] = make_float4(fmaxf(acc[4],0.f), fmaxf(acc[5],0.f),
                                            fmaxf(acc[6],0.f), fmaxf(acc[7],0.f));
        }
    }
}

// Whole pipeline in one persistent kernel: cvt -> gbar -> L1 -> gbar -> L2.
// Saves 2 kernel launches (~13 us each per the overhead model).
__global__ __launch_bounds__(256, 6)
void sage_all(const float4* __restrict__ emb4,       // [N*8] f32x4
              const float*  __restrict__ W1,
              const float*  __restrict__ W2,
              const int*    __restrict__ node_batch, // [B]
              const int*    __restrict__ neigh,      // [N,10]
              unsigned short* __restrict__ emb_bf,   // ws: [N,32] bf16
              unsigned short* __restrict__ h1_bf,    // ws: [N,32] bf16
              float*        __restrict__ out,        // [B,32] f32
              int N, int B)
{
    __shared__ float sh[64][65];          // 16640 B
    __shared__ int   s_nb[64][KN];        //  2560 B
    __shared__ int   s_node[64];          //   256 B   -> 19456 B total

    const int tid = threadIdx.x;

    // ---- phase 0: emb f32 -> bf16 (streaming) ----
    {
        ushort4* ob = (ushort4*)emb_bf;
        const int n4 = N * (EMBD / 4);
        for (int i = blockIdx.x * 256 + tid; i < n4; i += gridDim.x * 256) {
            float4 v = emb4[i];
            ushort4 o;
            o.x = f2bf(v.x); o.y = f2bf(v.y); o.z = f2bf(v.z); o.w = f2bf(v.w);
            ob[i] = o;
        }
    }
    gbar();

    // ---- phase 1: layer 1 over all N nodes, h1 bf16 ----
    {
        const int nt = (N + 63) >> 6;
        for (int t = blockIdx.x; t < nt; t += gridDim.x)
            sage_tile<false, true>(emb_bf, W1, neigh, nullptr,
                                   (void*)h1_bf, N, t, sh, s_nb, s_node);
    }
    gbar();

    // ---- phase 2: layer 2 over batch rows, f32 out ----
    {
        const int nt = (B + 63) >> 6;
        for (int t = blockIdx.x; t < nt; t += gridDim.x)
            sage_tile<true, false>(h1_bf, W2, neigh, node_batch,
                                   (void*)out, B, t, sh, s_nb, s_node);
    }
}

extern "C" void kernel_launch(void* const* d_in, const int* in_sizes, int n_in,
                              void* d_out, int out_size, void* d_ws, size_t ws_size,
                              hipStream_t stream)
{
    // dict order: emb [N,32] f32, W1 [32,64] f32, W2 [32,64] f32,
    //             node_batch [B] i32, neigh [N,10] i32
    const float* emb        = (const float*)d_in[0];
    const float* W1         = (const float*)d_in[1];
    const float* W2         = (const float*)d_in[2];
    const int*   node_batch = (const int*)  d_in[3];
    const int*   neigh      = (const int*)  d_in[4];

    const int N = in_sizes[0] / EMBD;   // 500000
    const int B = in_sizes[3];          // 100000

    unsigned short* emb_bf = (unsigned short*)d_ws;              // 32 MB
    unsigned short* h1_bf  = emb_bf + (size_t)N * EMBD;          // 32 MB

    sage_all<<<NBLK, 256, 0, stream>>>(
        (const float4*)emb, W1, W2, node_batch, neigh,
        emb_bf, h1_bf, (float*)d_out, N, B);
}

// Round 4
// 575.564 us; speedup vs baseline: 1.5609x; 1.5609x over previous
//
#include <hip/hip_runtime.h>

#define EMBD 32
#define KN 10
#define NBLK 1536   // 6 blocks/CU x 256 CU; residency guaranteed (see launch_bounds note)

__device__ unsigned int g_cnt   = 0;
__device__ unsigned int g_epoch = 0;

__device__ __forceinline__ float bf2f(unsigned short u) {
    union { unsigned int u; float f; } c; c.u = ((unsigned int)u) << 16; return c.f;
}
__device__ __forceinline__ unsigned short f2bf(float f) {
    union { float f; unsigned int u; } c; c.f = f;
    unsigned int u = c.u + 0x7FFFu + ((c.u >> 16) & 1u);   // RNE
    return (unsigned short)(u >> 16);
}

// Device-scope epoch barrier, v2. R3's version spun on ACQUIRE loads: on
// gfx950 every acquire at agent scope emits buffer_inv (XCD-wide L2
// invalidate) -> ~1400 spinners continuously blew away all 8 L2s while
// stragglers finished their last tile (positive feedback; 6x collapse).
// v2 steady-state touches NO cache-maintenance ops:
//   - arrive: one ACQ_REL fetch_add (release: one buffer_wbl2 per block,
//     flushing this XCD's L2 -- covers all the block's prior stores since
//     __syncthreads() already drained them to L2)
//   - spin:   RELAXED agent atomic loads (global_load sc1: reads the
//     coherence point directly, NO invalidate)
//   - exit:   exactly one acquire fence (buffer_inv) per block
// Monotone epoch -> safe across graph replays / rocprof counter-group
// replays (no per-launch state reset). Plain atomics, no cooperative API.
// Correct only if ALL gridDim.x blocks are resident: launch_bounds(256,6)
// (VGPR cap 85, actual 40) + LDS 19456 B/block (6 x 19.5 KB = 117 KB <=
// 160 KB/CU) with grid = 6 blocks/CU x 256 CU.
__device__ __forceinline__ void gbar() {
    __syncthreads();                       // all block's stores issued & in L2
    if (threadIdx.x == 0) {
        unsigned int e = __hip_atomic_load(&g_epoch, __ATOMIC_RELAXED,
                                           __HIP_MEMORY_SCOPE_AGENT);
        unsigned int a = __hip_atomic_fetch_add(&g_cnt, 1u, __ATOMIC_ACQ_REL,
                                                __HIP_MEMORY_SCOPE_AGENT);
        if (a == gridDim.x - 1) {          // last arriver
            __hip_atomic_store(&g_cnt, 0u, __ATOMIC_RELAXED,
                               __HIP_MEMORY_SCOPE_AGENT);
            __hip_atomic_fetch_add(&g_epoch, 1u, __ATOMIC_RELEASE,
                                   __HIP_MEMORY_SCOPE_AGENT);
        } else {
            while (__hip_atomic_load(&g_epoch, __ATOMIC_RELAXED,
                                     __HIP_MEMORY_SCOPE_AGENT) == e)
                __builtin_amdgcn_s_sleep(8);
            __builtin_amdgcn_fence(__ATOMIC_ACQUIRE, "agent");  // one inv
        }
    }
    __syncthreads();
}

// One fused SAGE tile (64 rows): index-stage -> gather-mean -> GEMM+ReLU.
// Body identical to the round-1 kernel (96 us/L1 = the ~3.5 TB/s random
// 64 B-gather pattern ceiling, verified across 3 structures in R0-R2).
template<bool REMAP, bool OUT_BF16>
__device__ __forceinline__ void sage_tile(
    const unsigned short* __restrict__ feat,  // [n_nodes,32] bf16
    const float*          __restrict__ W,     // [32][64] f32
    const int*            __restrict__ neigh, // [N_NODES,10]
    const int*            __restrict__ remap, // row -> node (REMAP)
    void*                 __restrict__ out,   // [n_rows,32]
    int n_rows, int tile,
    float (* __restrict__ sh)[65],
    int   (* __restrict__ s_nb)[KN],
    int*     __restrict__ s_node)
{
    const int tid  = threadIdx.x;
    const int row0 = tile << 6;

    __syncthreads();                      // protect LDS from previous tile's readers

    if constexpr (REMAP) {
        if (tid < 64) {
            int r = row0 + tid;
            if (r >= n_rows) r = n_rows - 1;       // clamp; store guarded later
            s_node[tid] = remap[r];
        }
        __syncthreads();
    }

    // stage all 640 neighbor ids, fully parallel
    #pragma unroll
    for (int e = tid; e < 64 * KN; e += 256) {
        const int rl = e / KN;
        const int k  = e - rl * KN;
        int node;
        if constexpr (REMAP) node = s_node[rl];
        else { int r = row0 + rl; node = (r >= n_rows) ? n_rows - 1 : r; }
        s_nb[rl][k] = neigh[node * KN + k];
    }
    __syncthreads();

    // gather: half-wave per row, 64 B coalesced bf16 rows
    {
        const int hw = tid >> 5;
        const int j  = tid & 31;
        #pragma unroll 2
        for (int i = 0; i < 8; ++i) {
            const int rl = hw * 8 + i;
            int node;
            if constexpr (REMAP) node = s_node[rl];
            else { int r = row0 + rl; node = (r >= n_rows) ? n_rows - 1 : r; }
            const float self = bf2f(feat[node * EMBD + j]);
            float agg = 0.f;
            #pragma unroll
            for (int k = 0; k < KN; ++k)
                agg += bf2f(feat[s_nb[rl][k] * EMBD + j]);
            sh[j][rl]      = self;
            sh[32 + j][rl] = agg * 0.1f;
        }
    }
    __syncthreads();

    // compute: wave wid -> outputs [8wid, 8wid+8) for all 64 rows
    const int row = tid & 63;
    const int wid = __builtin_amdgcn_readfirstlane(tid >> 6);
    const float* Wb = W + wid * 8 * 64;   // wave-uniform -> scalar K$ loads

    float acc[8] = {0.f,0.f,0.f,0.f,0.f,0.f,0.f,0.f};
    #pragma unroll 8
    for (int jj = 0; jj < 64; ++jj) {
        const float c = sh[jj][row];      // stride-1 across lanes: conflict-free
        #pragma unroll
        for (int q = 0; q < 8; ++q)
            acc[q] = fmaf(c, Wb[q * 64 + jj], acc[q]);
    }

    const int r = row0 + row;
    if (r < n_rows) {
        if constexpr (OUT_BF16) {
            unsigned int pk[4];
            #pragma unroll
            for (int q = 0; q < 4; ++q) {
                float a0 = fmaxf(acc[2*q],     0.f);
                float a1 = fmaxf(acc[2*q + 1], 0.f);
                pk[q] = (unsigned int)f2bf(a0) | ((unsigned int)f2bf(a1) << 16);
            }
            uint4* dst = (uint4*)((unsigned short*)out + (size_t)r * EMBD + wid * 8);
            *dst = make_uint4(pk[0], pk[1], pk[2], pk[3]);
        } else {
            float* dst = (float*)out + (size_t)r * EMBD + wid * 8;
            ((float4*)dst)[0] = make_float4(fmaxf(acc[0],0.f), fmaxf(acc[1],0.f),
                                            fmaxf(acc[2],0.f), fmaxf(acc[3],0.f));
            ((float4*)dst)[1] = make_float4(fmaxf(acc[4],0.f), fmaxf(acc[5],0.f),
                                            fmaxf(acc[6],0.f), fmaxf(acc[7],0.f));
        }
    }
}

// Whole pipeline in one persistent kernel: cvt -> gbar -> L1 -> gbar -> L2.
// Saves ~2 x 24 us of launch gap (measured across R1/R2/R3 gap accounting).
__global__ __launch_bounds__(256, 6)
void sage_all(const float4* __restrict__ emb4,       // [N*8] f32x4
              const float*  __restrict__ W1,
              const float*  __restrict__ W2,
              const int*    __restrict__ node_batch, // [B]
              const int*    __restrict__ neigh,      // [N,10]
              unsigned short* __restrict__ emb_bf,   // ws: [N,32] bf16
              unsigned short* __restrict__ h1_bf,    // ws: [N,32] bf16
              float*        __restrict__ out,        // [B,32] f32
              int N, int B)
{
    __shared__ float sh[64][65];          // 16640 B
    __shared__ int   s_nb[64][KN];        //  2560 B
    __shared__ int   s_node[64];          //   256 B   -> 19456 B total

    const int tid = threadIdx.x;

    // ---- phase 0: emb f32 -> bf16 (streaming) ----
    {
        ushort4* ob = (ushort4*)emb_bf;
        const int n4 = N * (EMBD / 4);
        for (int i = blockIdx.x * 256 + tid; i < n4; i += gridDim.x * 256) {
            float4 v = emb4[i];
            ushort4 o;
            o.x = f2bf(v.x); o.y = f2bf(v.y); o.z = f2bf(v.z); o.w = f2bf(v.w);
            ob[i] = o;
        }
    }
    gbar();

    // ---- phase 1: layer 1 over all N nodes, h1 bf16 ----
    {
        const int nt = (N + 63) >> 6;
        for (int t = blockIdx.x; t < nt; t += gridDim.x)
            sage_tile<false, true>(emb_bf, W1, neigh, nullptr,
                                   (void*)h1_bf, N, t, sh, s_nb, s_node);
    }
    gbar();

    // ---- phase 2: layer 2 over batch rows, f32 out ----
    {
        const int nt = (B + 63) >> 6;
        for (int t = blockIdx.x; t < nt; t += gridDim.x)
            sage_tile<true, false>(h1_bf, W2, neigh, node_batch,
                                   (void*)out, B, t, sh, s_nb, s_node);
    }
}

extern "C" void kernel_launch(void* const* d_in, const int* in_sizes, int n_in,
                              void* d_out, int out_size, void* d_ws, size_t ws_size,
                              hipStream_t stream)
{
    // dict order: emb [N,32] f32, W1 [32,64] f32, W2 [32,64] f32,
    //             node_batch [B] i32, neigh [N,10] i32
    const float* emb        = (const float*)d_in[0];
    const float* W1         = (const float*)d_in[1];
    const float* W2         = (const float*)d_in[2];
    const int*   node_batch = (const int*)  d_in[3];
    const int*   neigh      = (const int*)  d_in[4];

    const int N = in_sizes[0] / EMBD;   // 500000
    const int B = in_sizes[3];          // 100000

    unsigned short* emb_bf = (unsigned short*)d_ws;              // 32 MB
    unsigned short* h1_bf  = emb_bf + (size_t)N * EMBD;          // 32 MB

    sage_all<<<NBLK, 256, 0, stream>>>(
        (const float4*)emb, W1, W2, node_batch, neigh,
        emb_bf, h1_bf, (float*)d_out, N, B);
}

// Round 5
// 229.977 us; speedup vs baseline: 3.9064x; 2.5027x over previous
//
#include <hip/hip_runtime.h>

#define EMBD 32
#define KN 10

__device__ __forceinline__ float bf2f(unsigned short u) {
    union { unsigned int u; float f; } c; c.u = ((unsigned int)u) << 16; return c.f;
}
__device__ __forceinline__ unsigned short f2bf(float f) {
    union { float f; unsigned int u; } c; c.f = f;
    unsigned int u = c.u + 0x7FFFu + ((c.u >> 16) & 1u);   // RNE
    return (unsigned short)(u >> 16);
}
__device__ __forceinline__ float bflo(unsigned int u) {   // low bf16 of a uint
    union { unsigned int u; float f; } c; c.u = u << 16; return c.f;
}
__device__ __forceinline__ float bfhi(unsigned int u) {   // high bf16 of a uint
    union { unsigned int u; float f; } c; c.u = u & 0xffff0000u; return c.f;
}

// f32 -> bf16 table conversion (streaming, ~96 MB traffic)
__global__ __launch_bounds__(256)
void cvt_bf16_kernel(const float4* __restrict__ in, ushort4* __restrict__ out, int n4)
{
    int i = blockIdx.x * 256 + threadIdx.x;
    if (i < n4) {
        float4 v = in[i];
        ushort4 o;
        o.x = f2bf(v.x); o.y = f2bf(v.y); o.z = f2bf(v.z); o.w = f2bf(v.w);
        out[i] = o;
    }
}

// One SAGE layer, 64 rows per 256-thread block. 3-launch structure (proven
// 232 us total in R1; persistent-kernel variants R3/R4 were 2-4x worse).
//
// VECTORIZED GATHER (new vs R1): R0-R2 all gathered with per-lane ushort
// loads (88 load-instructions/thread, 2 cache lines per wave-instruction)
// and all plateaued at ~3.5 TB/s. This version gathers quarter-rows:
// thread (g = tid>>2, q = tid&3) loads the 16 B quarter q of each feature
// row for row-slot g -> global_load_dwordx4, 16 lines per wave-instruction,
// 11 loads/thread total. Lines-in-flight per wave rises ~8x; if the 3.5 TB/s
// plateau was concurrency/issue-limited this breaks it, if it's fabric BW
// it will reproduce exactly (-> roofline confirmed).
//
// Index staging: Phase A node ids, Phase B all 640 neighbor ids (parallel,
// coalesced), so gather addresses depend only on LDS.
// LDS writes sh[f][g], f = 8q+e: bank (f+g)&31 -> exactly 2-way = free.
// Compute: wave wid -> outputs [8wid,8wid+8), comb streamed from LDS,
// W base wave-uniform via readfirstlane -> scalar K$ loads.
template<bool REMAP, bool OUT_BF16>
__global__ __launch_bounds__(256, 4)
void sage_layer(const unsigned short* __restrict__ feat, // [n_nodes, 32] bf16
                const float* __restrict__ W,             // [32][64] f32
                const int*   __restrict__ neigh,         // [N_NODES, 10]
                const int*   __restrict__ remap,         // row -> node (REMAP)
                void*        __restrict__ out,           // [n_rows, 32]
                int n_rows)
{
    __shared__ float sh[64][65];          // 16640 B
    __shared__ int   s_nb[64][KN];        //  2560 B
    __shared__ int   s_node[64];          //   256 B

    const int tid  = threadIdx.x;
    const int row0 = blockIdx.x << 6;

    // ---- Phase A: node ids ----
    if constexpr (REMAP) {
        if (tid < 64) {
            int r = row0 + tid;
            if (r >= n_rows) r = n_rows - 1;       // clamp; store guarded later
            s_node[tid] = remap[r];                // coalesced 256 B
        }
        __syncthreads();
    }

    // ---- Phase B: stage all 640 neighbor ids, fully parallel ----
    #pragma unroll
    for (int e = tid; e < 64 * KN; e += 256) {
        const int rl = e / KN;
        const int k  = e - rl * KN;
        int node;
        if constexpr (REMAP) node = s_node[rl];
        else { int r = row0 + rl; node = (r >= n_rows) ? n_rows - 1 : r; }
        s_nb[rl][k] = neigh[node * KN + k];        // layer1: contiguous 2.5 KB
    }
    __syncthreads();

    // ---- Phase C: vectorized gather. thread (g,q): quarter q of row-slot g.
    {
        const int g = tid >> 2;           // row slot 0..63
        const int q = tid & 3;            // 16 B quarter of the 64 B row
        int node;
        if constexpr (REMAP) node = s_node[g];
        else { int r = row0 + g; node = (r >= n_rows) ? n_rows - 1 : r; }

        const uint4* base = (const uint4*)feat;    // row = 4 x uint4

        // issue all 11 dwordx4 loads; addresses depend only on LDS
        uint4 sv = base[(size_t)node * 4 + q];     // self quarter
        uint4 nv[KN];
        #pragma unroll
        for (int k = 0; k < KN; ++k)
            nv[k] = base[(size_t)s_nb[g][k] * 4 + q];

        float a0=0.f,a1=0.f,a2=0.f,a3=0.f,a4=0.f,a5=0.f,a6=0.f,a7=0.f;
        #pragma unroll
        for (int k = 0; k < KN; ++k) {
            a0 += bflo(nv[k].x); a1 += bfhi(nv[k].x);
            a2 += bflo(nv[k].y); a3 += bfhi(nv[k].y);
            a4 += bflo(nv[k].z); a5 += bfhi(nv[k].z);
            a6 += bflo(nv[k].w); a7 += bfhi(nv[k].w);
        }

        const int f0 = q * 8;             // first feature of this quarter
        sh[f0+0][g] = bflo(sv.x); sh[f0+1][g] = bfhi(sv.x);
        sh[f0+2][g] = bflo(sv.y); sh[f0+3][g] = bfhi(sv.y);
        sh[f0+4][g] = bflo(sv.z); sh[f0+5][g] = bfhi(sv.z);
        sh[f0+6][g] = bflo(sv.w); sh[f0+7][g] = bfhi(sv.w);
        sh[32+f0+0][g] = a0 * 0.1f; sh[32+f0+1][g] = a1 * 0.1f;
        sh[32+f0+2][g] = a2 * 0.1f; sh[32+f0+3][g] = a3 * 0.1f;
        sh[32+f0+4][g] = a4 * 0.1f; sh[32+f0+5][g] = a5 * 0.1f;
        sh[32+f0+6][g] = a6 * 0.1f; sh[32+f0+7][g] = a7 * 0.1f;
    }
    __syncthreads();

    // ---- compute phase: wave wid -> outputs [8*wid, 8*wid+8) ----
    const int row = tid & 63;
    const int wid = __builtin_amdgcn_readfirstlane(tid >> 6);
    const float* Wb = W + wid * 8 * 64;   // wave-uniform -> scalar K$ loads

    float acc[8] = {0.f,0.f,0.f,0.f,0.f,0.f,0.f,0.f};
    #pragma unroll 8
    for (int jj = 0; jj < 64; ++jj) {
        const float c = sh[jj][row];      // stride-1 across lanes: conflict-free
        #pragma unroll
        for (int q = 0; q < 8; ++q)
            acc[q] = fmaf(c, Wb[q * 64 + jj], acc[q]);
    }

    const int r = row0 + row;
    if (r < n_rows) {
        if constexpr (OUT_BF16) {
            unsigned int pk[4];
            #pragma unroll
            for (int q = 0; q < 4; ++q) {
                float a0 = fmaxf(acc[2*q],     0.f);
                float a1 = fmaxf(acc[2*q + 1], 0.f);
                pk[q] = (unsigned int)f2bf(a0) | ((unsigned int)f2bf(a1) << 16);
            }
            uint4* dst = (uint4*)((unsigned short*)out + (size_t)r * EMBD + wid * 8);
            *dst = make_uint4(pk[0], pk[1], pk[2], pk[3]);
        } else {
            float* dst = (float*)out + (size_t)r * EMBD + wid * 8;
            ((float4*)dst)[0] = make_float4(fmaxf(acc[0],0.f), fmaxf(acc[1],0.f),
                                            fmaxf(acc[2],0.f), fmaxf(acc[3],0.f));
            ((float4*)dst)[1] = make_float4(fmaxf(acc[4],0.f), fmaxf(acc[5],0.f),
                                            fmaxf(acc[6],0.f), fmaxf(acc[7],0.f));
        }
    }
}

extern "C" void kernel_launch(void* const* d_in, const int* in_sizes, int n_in,
                              void* d_out, int out_size, void* d_ws, size_t ws_size,
                              hipStream_t stream)
{
    // dict order: emb [N,32] f32, W1 [32,64] f32, W2 [32,64] f32,
    //             node_batch [B] i32, neigh [N,10] i32
    const float* emb        = (const float*)d_in[0];
    const float* W1         = (const float*)d_in[1];
    const float* W2         = (const float*)d_in[2];
    const int*   node_batch = (const int*)  d_in[3];
    const int*   neigh      = (const int*)  d_in[4];

    const int N = in_sizes[0] / EMBD;   // 500000
    const int B = in_sizes[3];          // 100000

    unsigned short* emb_bf = (unsigned short*)d_ws;              // 32 MB
    unsigned short* h1_bf  = emb_bf + (size_t)N * EMBD;          // 32 MB

    // 1) emb f32 -> bf16
    const int n4 = (N * EMBD) / 4;
    cvt_bf16_kernel<<<(n4 + 255) / 256, 256, 0, stream>>>(
        (const float4*)emb, (ushort4*)emb_bf, n4);

    // 2) layer 1: all N nodes, h1 stored bf16
    sage_layer<false, true><<<(N + 63) / 64, 256, 0, stream>>>(
        emb_bf, W1, neigh, nullptr, (void*)h1_bf, N);

    // 3) layer 2: batch rows, f32 output
    sage_layer<true, false><<<(B + 63) / 64, 256, 0, stream>>>(
        h1_bf, W2, neigh, node_batch, d_out, B);
}